// Round 4
// baseline (948.238 us; speedup 1.0000x reference)
//
#include <hip/hip_runtime.h>
#include <math.h>

#define W    3072
#define HH   3072
#define HOUT 3060       // HH - 12 (valid conv output for 13x13 kernel)
#define TW   64         // output cols per block
#define TH   56         // output rows per block (4 waves x 14 rows)
#define XR   68         // xt rows = TH + 12
#define XTS  76         // xt col stride
#define VTS  77         // vt col stride (odd -> scalar reads/writes conflict-free)
#define VTW  (14*VTS)   // per-wave vt words = 1078
#define GX   48
#define GY   55
#define GZ   2
#define NTHR (GX*GY*GZ*256)

struct HessTaps { float a[13]; float bb[13]; float m[13]; float n[13]; };

// per-wave shuffle reduce -> one f64 atomic per wave (no barriers, no LDS)
__device__ __forceinline__ void wave_red_atomic(float v, double* a) {
  #pragma unroll
  for (int o = 32; o > 0; o >>= 1) v += __shfl_down(v, o, 64);
  if ((threadIdx.x & 63) == 0) unsafeAtomicAdd(a, (double)v);
}

// ---- Hessian + TV + folded gf/mse, both images via gridDim.z ---------------
// 64x56 output tile, 4 waves x 14 rows each, wave-local V->H (vt is
// wave-private), scalar f32 FMAs throughout (v_pk_fma_f32 is half-rate on
// gfx950 -- fp32 peak equals scalar-FMA full rate -- so packing f32 buys no
// cycles; rounds 1-2 verified this the hard way).
//  * V main: lane = col (64 cols, all lanes useful), 14 sliding accumulators,
//    26 contiguous scalar LDS reads; 182 FMAs.
//  * V halo: 12 cols x 14 rows = 168 outputs mapped 3-per-lane (dense!),
//    39 FMAs vs round-0's 208-slot mostly-dead halo chain.
//  * H: lane (row r14<14, colgroup cg), 28 scalar sliding reads at stride 77
//    (<=2 lanes/bank, free), 208 FMAs, results stay in registers.
//  * gf/mse global loads issued BEFORE the first barrier (scalars + float4s
//    only -- no arrays, no spill), consumed at the very end.
// LDS: xt 68*76*4=20672 + vt 4*1078*4=17248 = 37920 B -> 4 blocks/CU.
__global__ __launch_bounds__(256, 4) void hess_kernel(const float* __restrict__ Gnn,
                                                      const float* __restrict__ Lr,
                                                      const float* __restrict__ T,
                                                      const float* __restrict__ Xr,
                                                      const float* __restrict__ St,
                                                      const float* __restrict__ Mp,
                                                      double* acc, HessTaps tp) {
  __shared__ float xt[XR * XTS];
  __shared__ float vt[4 * VTW];
  const float* img = (blockIdx.z == 0) ? Gnn : Lr;
  int oy = blockIdx.y * TH, ox = blockIdx.x * TW;
  int t = threadIdx.x;
  int wv = t >> 6, ln = t & 63;    // wave id 0..3, lane 0..63
  int r0 = wv * 14;

  // load xt (68 rows x 76 cols) as aligned float4 with edge masking
  for (int idx = t; idx < XR * 19; idx += 256) {
    int r = idx / 19, g = idx - r * 19;
    int gr = oy + r, gc = ox + 4 * g;
    float4 v = {0.f, 0.f, 0.f, 0.f};
    if (gr < HH) {
      const float* p = &img[(size_t)gr * W + gc];
      if (gc + 3 < W) v = *(const float4*)p;
      else {
        if (gc < W)     v.x = p[0];
        if (gc + 1 < W) v.y = p[1];
        if (gc + 2 < W) v.z = p[2];
      }
    }
    *(float4*)&xt[r * XTS + 4 * g] = v;
  }

  // ---- issue gf/mse global loads now; latency hides under the whole conv
  int bid = (blockIdx.z * GY + blockIdx.y) * GX + blockIdx.x;
  int i0 = bid * 256 + t;
  int i1 = i0 + NTHR;
  const int n4 = (W * HH) / 4;
  float4 ga0 = ((const float4*)Xr)[i0];    // i0 < NTHR <= n4 always
  float4 gb0 = ((const float4*)St)[i0];
  float4 ga1 = {0.f, 0.f, 0.f, 0.f}, gb1 = ga1;
  bool has1 = (i1 < n4);
  if (has1) { ga1 = ((const float4*)Xr)[i1]; gb1 = ((const float4*)St)[i1]; }
  float mT = 0.f, mG = 0.f, mM = 0.f;
  bool hasm = (i0 < 384 * 384);
  if (hasm) {
    int si = i0 / 384, sj = i0 - si * 384;
    int id = si * 8 * W + sj * 8;
    mT = T[id]; mG = Gnn[id]; mM = Mp[id];
  }
  __builtin_amdgcn_sched_barrier(0);

  __syncthreads();     // barrier 1: xt staged

  float tvl = 0.f;   // TV accumulator
  float hl  = 0.f;   // Hessian accumulator

  // TV Dx term on x: |x(r,c) - x(r,c+1)|  (lanes contiguous -> free)
  {
    int gc = ox + ln;
    if (gc < W - 1) {
      #pragma unroll
      for (int i = 0; i < 14; ++i) {
        int r = r0 + i;
        if (oy + r < HH)
          tvl += fabsf(xt[r * XTS + ln] - xt[r * XTS + ln + 1]);
      }
    }
  }

  // ---- V pass: main 64 cols (all lanes) + dense halo (3 outputs/lane).
  // Per-output tap order u-ascending -> bitwise identical to rounds 0-3.
  #define VPASS(TAP)                                                        \
    {                                                                       \
      /* main: lane = col ln; 14 sliding accumulators over 26-row window */ \
      float oA[14];                                                         \
      _Pragma("unroll")                                                     \
      for (int i = 0; i < 14; ++i) oA[i] = 0.f;                             \
      _Pragma("unroll")                                                     \
      for (int u = 0; u < 26; ++u) {                                        \
        float xA = xt[(r0 + u) * XTS + ln];                                 \
        _Pragma("unroll")                                                   \
        for (int i = 0; i < 14; ++i) {                                      \
          int kk = u - i;                                                   \
          if (kk >= 0 && kk <= 12) oA[i] = fmaf((TAP)[kk], xA, oA[i]);      \
        }                                                                   \
      }                                                                     \
      float* vw = &vt[wv * VTW + ln];                                       \
      _Pragma("unroll")                                                     \
      for (int i = 0; i < 14; ++i) vw[i * VTS] = oA[i];                     \
      /* halo: 12 cols x 14 rows = 168 outputs, 3 per lane, dense issue */  \
      _Pragma("unroll")                                                     \
      for (int k = 0; k < 3; ++k) {                                         \
        int o = ln + 64 * k;                                                \
        if (o < 168) {                                                      \
          int row = o / 12, hc = o - row * 12;                              \
          const float* xp = &xt[(r0 + row) * XTS + 64 + hc];                \
          float s = 0.f;                                                    \
          _Pragma("unroll")                                                 \
          for (int u = 0; u < 13; ++u) s = fmaf((TAP)[u], xp[u * XTS], s);  \
          vt[wv * VTW + row * VTS + 64 + hc] = s;                           \
        }                                                                   \
      }                                                                     \
    }

  // ---- H pass: scalar sliding reads of the SAME wave's vt rows (stride 77
  // -> <=2 lanes/bank); 16 register accumulators, tap order j-ascending.
  #define HSECOND(TAP, WGT)                                                 \
    {                                                                       \
      int r14 = ln & 15, cg = ln >> 4;                                      \
      if (r14 < 14) {                                                       \
        const float* vrow = &vt[wv * VTW + r14 * VTS + cg * 16];            \
        float o_[16];                                                       \
        _Pragma("unroll")                                                   \
        for (int jj = 0; jj < 16; ++jj) o_[jj] = 0.f;                       \
        _Pragma("unroll")                                                   \
        for (int j = 0; j < 28; ++j) {                                      \
          float v = vrow[j];                                                \
          _Pragma("unroll")                                                 \
          for (int jj = 0; jj < 16; ++jj) {                                 \
            int kk = j - jj;                                                \
            if (kk >= 0 && kk <= 12) o_[jj] = fmaf((TAP)[kk], v, o_[jj]);   \
          }                                                                 \
        }                                                                   \
        int gr = oy + r0 + r14;                                             \
        int gc0 = ox + cg * 16;                                             \
        float wr = (gr < HOUT) ? (WGT) : 0.f;                               \
        _Pragma("unroll")                                                   \
        for (int jj = 0; jj < 16; ++jj) {                                   \
          float m_ = (gc0 + jj < HOUT) ? wr : 0.f;                          \
          hl = fmaf(m_, fabsf(o_[jj]), hl);                                 \
        }                                                                   \
      }                                                                     \
    }

  // term 1: conv(x, Gxx) = vert bb, horiz a   (vt is wave-private: no barrier)
  VPASS(tp.bb);
  HSECOND(tp.a, 1.0f);

  // d = x - target (in place); all waves must be done reading xt first
  __syncthreads();     // barrier 2
  for (int idx = t; idx < XR * 19; idx += 256) {
    int r = idx / 19, g = idx - r * 19;
    int gr = oy + r, gc = ox + 4 * g;
    float4 v = {0.f, 0.f, 0.f, 0.f};
    if (gr < HH) {
      const float* p = &T[(size_t)gr * W + gc];
      if (gc + 3 < W) v = *(const float4*)p;
      else {
        if (gc < W)     v.x = p[0];
        if (gc + 1 < W) v.y = p[1];
        if (gc + 2 < W) v.z = p[2];
      }
    }
    float4 cur = *(float4*)&xt[r * XTS + 4 * g];
    cur.x -= v.x; cur.y -= v.y; cur.z -= v.z; cur.w -= v.w;
    *(float4*)&xt[r * XTS + 4 * g] = cur;
  }
  __syncthreads();     // barrier 3

  // TV Dy term on d: |d(r,c) - d(r+1,c)|, r < HH-1
  {
    int gc = ox + ln;
    if (gc < W) {
      #pragma unroll
      for (int i = 0; i < 14; ++i) {
        int r = r0 + i;
        if (oy + r < HH - 1)
          tvl += fabsf(xt[r * XTS + ln] - xt[(r + 1) * XTS + ln]);
      }
    }
  }

  // term 2: conv(d, Gyy) = vert a, horiz bb
  VPASS(tp.a);
  HSECOND(tp.bb, 1.0f);

  // term 3: conv(d, Gxy) = vert m, horiz n, weight 2 (isotropic)
  VPASS(tp.m);
  HSECOND(tp.n, 2.0f);

  // folded gf term (gf(x,x)==x exactly -> sum|st-x|) + sampled L1*map;
  // operands loaded before barrier 1, long dead-register-free latency window.
  float gm = fabsf(gb0.x - ga0.x) + fabsf(gb0.y - ga0.y)
           + fabsf(gb0.z - ga0.z) + fabsf(gb0.w - ga0.w);
  if (has1)
    gm += fabsf(gb1.x - ga1.x) + fabsf(gb1.y - ga1.y)
        + fabsf(gb1.z - ga1.z) + fabsf(gb1.w - ga1.w);
  if (hasm) gm += fabsf(mT - mG) * mM;

  wave_red_atomic(tvl, &acc[1]);
  wave_red_atomic(hl,  &acc[3]);
  wave_red_atomic(gm,  &acc[0]);
}

// ---- combine ---------------------------------------------------------------
__global__ void finalize_kernel(const double* acc, float* out) {
  out[0] = (float)(acc[0] + acc[2] + 0.1 * acc[1] + 0.5 * acc[3]);
}

extern "C" void kernel_launch(void* const* d_in, const int* in_sizes, int n_in,
                              void* d_out, int out_size, void* d_ws, size_t ws_size,
                              hipStream_t stream) {
  const float* xraw = (const float*)d_in[0];   // outputGNNraw
  const float* gnn  = (const float*)d_in[1];   // outputGNN
  const float* lr   = (const float*)d_in[2];   // outputLR
  const float* st   = (const float*)d_in[3];   // smoothedTarget
  const float* tg   = (const float*)d_in[4];   // targets
  const float* mp   = (const float*)d_in[5];   // map
  float* out = (float*)d_out;

  double* acc = (double*)d_ws;
  hipMemsetAsync(d_ws, 0, 32, stream);   // zero the 4 f64 accumulators

  // separable Hessian-of-Gaussian taps (sigma=1, t = -6..6):
  //   Gxx[i,j] = bb(i)*a(j); Gyy[i,j] = a(i)*bb(j); Gxy[i,j] = m(i)*n(j)
  HessTaps tp;
  const double PI2 = 6.283185307179586476925287;
  for (int k = 0; k < 13; ++k) {
    double tt = (double)(k - 6);
    double g = exp(-0.5 * tt * tt);
    tp.a[k]  = (float)((tt * tt - 1.0) * g / PI2);
    tp.bb[k] = (float)g;
    tp.m[k]  = (float)(tt * g / PI2);
    tp.n[k]  = (float)(tt * g);
  }

  // grid: 48 x-tiles * 55 y-tiles (55*56=3080 >= 3072, masked) * {GNN, LR}
  hess_kernel<<<dim3(GX, GY, GZ), 256, 0, stream>>>(gnn, lr, tg, xraw, st, mp,
                                                    acc, tp);

  finalize_kernel<<<1, 1, 0, stream>>>(acc, out);
}

// Round 5
// 285.758 us; speedup vs baseline: 3.3183x; 3.3183x over previous
//
#include <hip/hip_runtime.h>
#include <math.h>

#define W    3072
#define HH   3072
#define HOUT 3060       // HH - 12 (valid conv output for 13x13 kernel)
#define TW   64         // output cols per block
#define TH   56         // output rows per block (4 waves x 14 rows)
#define XR   68         // xt rows = TH + 12
#define XTS  76         // xt col stride
#define VTS  77         // vt col stride (odd -> scalar reads/writes conflict-free)
#define VTW  (14*VTS)   // per-wave vt words = 1078
#define GX   48
#define GY   55
#define GZ   2
#define NTHR (GX*GY*GZ*256)
#define NSLOT 64        // accumulator slots, each (slot,acc) on its own 64B line

struct HessTaps { float a[13]; float bb[13]; float m[13]; float n[13]; };

// ---- per-block reduction -> one f64 atomic per block ------------------------
// ATOMIC CONTENTION IS THE SESSION'S HIDDEN SERIALIZER: each f64 atomic is a
// 32B memory-side RMW (WRITE_SIZE = n_atomics*32 exactly, rounds 0-4); atomics
// to the SAME 64B line serialize at ~13ns. kernel_dur ~= hot-line atomics *
// 13ns fit rounds 0-4 within noise. Fix: block-level reduction (3 atomics) +
// slot-spreading across 64 lines -> ~250 atomics/line ~= 3us.
__device__ __forceinline__ void reduce_add(float v, double* a) {
  __shared__ float red[8];
  #pragma unroll
  for (int o = 32; o > 0; o >>= 1) v += __shfl_down(v, o, 64);
  int lane = threadIdx.x & 63, wid = threadIdx.x >> 6;
  if (lane == 0) red[wid] = v;
  __syncthreads();
  if (threadIdx.x == 0) {
    float s = red[0] + red[1] + red[2] + red[3];
    unsafeAtomicAdd(a, (double)s);
  }
  __syncthreads();   // protect red[] for a subsequent call
}

// ---- Hessian + TV + folded gf/mse, both images via gridDim.z ---------------
// 64x56 output tile, 4 waves x 14 rows each, wave-local V->H (vt is
// wave-private), scalar f32 FMAs throughout (v_pk_fma_f32 is half-rate on
// gfx950 -- fp32 peak equals scalar-FMA full rate -- so packing f32 buys no
// cycles; rounds 1-2 verified this the hard way).
//  * V main: lane = col (64 cols, all lanes useful), 14 sliding accumulators,
//    26 contiguous scalar LDS reads; 182 FMAs.
//  * V halo: 12 cols x 14 rows = 168 outputs mapped 3-per-lane (dense),
//    39 FMAs vs round-0's 208-slot mostly-dead halo chain.
//  * H: lane (row r14<14, colgroup cg), 28 scalar sliding reads at stride 77
//    (<=2 lanes/bank, free), 208 FMAs, results stay in registers.
//  * gf/mse global loads issued BEFORE the first barrier (scalars + float4s
//    only -- no arrays, no spill), consumed at the very end.
// LDS: xt 20672 + vt 17248 + red 32 = 37952 B -> 4 blocks/CU.
__global__ __launch_bounds__(256, 4) void hess_kernel(const float* __restrict__ Gnn,
                                                      const float* __restrict__ Lr,
                                                      const float* __restrict__ T,
                                                      const float* __restrict__ Xr,
                                                      const float* __restrict__ St,
                                                      const float* __restrict__ Mp,
                                                      double* acc, int slotmask,
                                                      HessTaps tp) {
  __shared__ float xt[XR * XTS];
  __shared__ float vt[4 * VTW];
  const float* img = (blockIdx.z == 0) ? Gnn : Lr;
  int oy = blockIdx.y * TH, ox = blockIdx.x * TW;
  int t = threadIdx.x;
  int wv = t >> 6, ln = t & 63;    // wave id 0..3, lane 0..63
  int r0 = wv * 14;

  // load xt (68 rows x 76 cols) as aligned float4 with edge masking
  for (int idx = t; idx < XR * 19; idx += 256) {
    int r = idx / 19, g = idx - r * 19;
    int gr = oy + r, gc = ox + 4 * g;
    float4 v = {0.f, 0.f, 0.f, 0.f};
    if (gr < HH) {
      const float* p = &img[(size_t)gr * W + gc];
      if (gc + 3 < W) v = *(const float4*)p;
      else {
        if (gc < W)     v.x = p[0];
        if (gc + 1 < W) v.y = p[1];
        if (gc + 2 < W) v.z = p[2];
      }
    }
    *(float4*)&xt[r * XTS + 4 * g] = v;
  }

  // ---- issue gf/mse global loads now; latency hides under the whole conv
  int bid = (blockIdx.z * GY + blockIdx.y) * GX + blockIdx.x;
  int i0 = bid * 256 + t;
  int i1 = i0 + NTHR;
  const int n4 = (W * HH) / 4;
  float4 ga0 = ((const float4*)Xr)[i0];    // i0 < NTHR <= n4 always
  float4 gb0 = ((const float4*)St)[i0];
  float4 ga1 = {0.f, 0.f, 0.f, 0.f}, gb1 = ga1;
  bool has1 = (i1 < n4);
  if (has1) { ga1 = ((const float4*)Xr)[i1]; gb1 = ((const float4*)St)[i1]; }
  float mT = 0.f, mG = 0.f, mM = 0.f;
  bool hasm = (i0 < 384 * 384);
  if (hasm) {
    int si = i0 / 384, sj = i0 - si * 384;
    int id = si * 8 * W + sj * 8;
    mT = T[id]; mG = Gnn[id]; mM = Mp[id];
  }
  __builtin_amdgcn_sched_barrier(0);

  __syncthreads();     // barrier 1: xt staged

  float tvl = 0.f;   // TV accumulator
  float hl  = 0.f;   // Hessian accumulator

  // TV Dx term on x: |x(r,c) - x(r,c+1)|  (lanes contiguous -> free)
  {
    int gc = ox + ln;
    if (gc < W - 1) {
      #pragma unroll
      for (int i = 0; i < 14; ++i) {
        int r = r0 + i;
        if (oy + r < HH)
          tvl += fabsf(xt[r * XTS + ln] - xt[r * XTS + ln + 1]);
      }
    }
  }

  // ---- V pass: main 64 cols (all lanes) + dense halo (3 outputs/lane).
  // Per-output tap order u-ascending -> bitwise identical to rounds 0-4.
  #define VPASS(TAP)                                                        \
    {                                                                       \
      /* main: lane = col ln; 14 sliding accumulators over 26-row window */ \
      float oA[14];                                                         \
      _Pragma("unroll")                                                     \
      for (int i = 0; i < 14; ++i) oA[i] = 0.f;                             \
      _Pragma("unroll")                                                     \
      for (int u = 0; u < 26; ++u) {                                        \
        float xA = xt[(r0 + u) * XTS + ln];                                 \
        _Pragma("unroll")                                                   \
        for (int i = 0; i < 14; ++i) {                                      \
          int kk = u - i;                                                   \
          if (kk >= 0 && kk <= 12) oA[i] = fmaf((TAP)[kk], xA, oA[i]);      \
        }                                                                   \
      }                                                                     \
      float* vw = &vt[wv * VTW + ln];                                       \
      _Pragma("unroll")                                                     \
      for (int i = 0; i < 14; ++i) vw[i * VTS] = oA[i];                     \
      /* halo: 12 cols x 14 rows = 168 outputs, 3 per lane, dense issue */  \
      _Pragma("unroll")                                                     \
      for (int k = 0; k < 3; ++k) {                                         \
        int o = ln + 64 * k;                                                \
        if (o < 168) {                                                      \
          int row = o / 12, hc = o - row * 12;                              \
          const float* xp = &xt[(r0 + row) * XTS + 64 + hc];                \
          float s = 0.f;                                                    \
          _Pragma("unroll")                                                 \
          for (int u = 0; u < 13; ++u) s = fmaf((TAP)[u], xp[u * XTS], s);  \
          vt[wv * VTW + row * VTS + 64 + hc] = s;                           \
        }                                                                   \
      }                                                                     \
    }

  // ---- H pass: scalar sliding reads of the SAME wave's vt rows (stride 77
  // -> <=2 lanes/bank); 16 register accumulators, tap order j-ascending.
  #define HSECOND(TAP, WGT)                                                 \
    {                                                                       \
      int r14 = ln & 15, cg = ln >> 4;                                      \
      if (r14 < 14) {                                                       \
        const float* vrow = &vt[wv * VTW + r14 * VTS + cg * 16];            \
        float o_[16];                                                       \
        _Pragma("unroll")                                                   \
        for (int jj = 0; jj < 16; ++jj) o_[jj] = 0.f;                       \
        _Pragma("unroll")                                                   \
        for (int j = 0; j < 28; ++j) {                                      \
          float v = vrow[j];                                                \
          _Pragma("unroll")                                                 \
          for (int jj = 0; jj < 16; ++jj) {                                 \
            int kk = j - jj;                                                \
            if (kk >= 0 && kk <= 12) o_[jj] = fmaf((TAP)[kk], v, o_[jj]);   \
          }                                                                 \
        }                                                                   \
        int gr = oy + r0 + r14;                                             \
        int gc0 = ox + cg * 16;                                             \
        float wr = (gr < HOUT) ? (WGT) : 0.f;                               \
        _Pragma("unroll")                                                   \
        for (int jj = 0; jj < 16; ++jj) {                                   \
          float m_ = (gc0 + jj < HOUT) ? wr : 0.f;                          \
          hl = fmaf(m_, fabsf(o_[jj]), hl);                                 \
        }                                                                   \
      }                                                                     \
    }

  // term 1: conv(x, Gxx) = vert bb, horiz a   (vt is wave-private: no barrier)
  VPASS(tp.bb);
  HSECOND(tp.a, 1.0f);

  // d = x - target (in place); all waves must be done reading xt first
  __syncthreads();     // barrier 2
  for (int idx = t; idx < XR * 19; idx += 256) {
    int r = idx / 19, g = idx - r * 19;
    int gr = oy + r, gc = ox + 4 * g;
    float4 v = {0.f, 0.f, 0.f, 0.f};
    if (gr < HH) {
      const float* p = &T[(size_t)gr * W + gc];
      if (gc + 3 < W) v = *(const float4*)p;
      else {
        if (gc < W)     v.x = p[0];
        if (gc + 1 < W) v.y = p[1];
        if (gc + 2 < W) v.z = p[2];
      }
    }
    float4 cur = *(float4*)&xt[r * XTS + 4 * g];
    cur.x -= v.x; cur.y -= v.y; cur.z -= v.z; cur.w -= v.w;
    *(float4*)&xt[r * XTS + 4 * g] = cur;
  }
  __syncthreads();     // barrier 3

  // TV Dy term on d: |d(r,c) - d(r+1,c)|, r < HH-1
  {
    int gc = ox + ln;
    if (gc < W) {
      #pragma unroll
      for (int i = 0; i < 14; ++i) {
        int r = r0 + i;
        if (oy + r < HH - 1)
          tvl += fabsf(xt[r * XTS + ln] - xt[(r + 1) * XTS + ln]);
      }
    }
  }

  // term 2: conv(d, Gyy) = vert a, horiz bb
  VPASS(tp.a);
  HSECOND(tp.bb, 1.0f);

  // term 3: conv(d, Gxy) = vert m, horiz n, weight 2 (isotropic)
  VPASS(tp.m);
  HSECOND(tp.n, 2.0f);

  // folded gf term (gf(x,x)==x exactly -> sum|st-x|) + sampled L1*map;
  // operands loaded before barrier 1, latency hidden under the conv.
  float gm = fabsf(gb0.x - ga0.x) + fabsf(gb0.y - ga0.y)
           + fabsf(gb0.z - ga0.z) + fabsf(gb0.w - ga0.w);
  if (has1)
    gm += fabsf(gb1.x - ga1.x) + fabsf(gb1.y - ga1.y)
        + fabsf(gb1.z - ga1.z) + fabsf(gb1.w - ga1.w);
  if (hasm) gm += fabsf(mT - mG) * mM;

  // slot-spread accumulators: (slot, j) at byte offset slot*256 + j*64
  // -> every target address on its own 64B line; ~250 atomics/line total.
  int slot = bid & slotmask;
  double* base = acc + (size_t)slot * 32;
  reduce_add(gm,  base);        // j=0
  reduce_add(tvl, base + 8);    // j=1
  reduce_add(hl,  base + 16);   // j=2
}

// ---- combine ---------------------------------------------------------------
__global__ void finalize_kernel(const double* acc, int slotmask, float* out) {
  double s0 = 0.0, s1 = 0.0, s3 = 0.0;
  for (int s = 0; s <= slotmask; ++s) {
    s0 += acc[s * 32];
    s1 += acc[s * 32 + 8];
    s3 += acc[s * 32 + 16];
  }
  out[0] = (float)(s0 + 0.1 * s1 + 0.5 * s3);
}

extern "C" void kernel_launch(void* const* d_in, const int* in_sizes, int n_in,
                              void* d_out, int out_size, void* d_ws, size_t ws_size,
                              hipStream_t stream) {
  const float* xraw = (const float*)d_in[0];   // outputGNNraw
  const float* gnn  = (const float*)d_in[1];   // outputGNN
  const float* lr   = (const float*)d_in[2];   // outputLR
  const float* st   = (const float*)d_in[3];   // smoothedTarget
  const float* tg   = (const float*)d_in[4];   // targets
  const float* mp   = (const float*)d_in[5];   // map
  float* out = (float*)d_out;

  // slot count: NSLOT if the workspace allows (needs NSLOT*256 B), else the
  // largest power of two that fits (>=1: 256 B minimum assumed available).
  int nslot = NSLOT;
  while (nslot > 1 && (size_t)nslot * 256 > ws_size) nslot >>= 1;
  int slotmask = nslot - 1;

  double* acc = (double*)d_ws;
  hipMemsetAsync(d_ws, 0, (size_t)nslot * 256, stream);

  // separable Hessian-of-Gaussian taps (sigma=1, t = -6..6):
  //   Gxx[i,j] = bb(i)*a(j); Gyy[i,j] = a(i)*bb(j); Gxy[i,j] = m(i)*n(j)
  HessTaps tp;
  const double PI2 = 6.283185307179586476925287;
  for (int k = 0; k < 13; ++k) {
    double tt = (double)(k - 6);
    double g = exp(-0.5 * tt * tt);
    tp.a[k]  = (float)((tt * tt - 1.0) * g / PI2);
    tp.bb[k] = (float)g;
    tp.m[k]  = (float)(tt * g / PI2);
    tp.n[k]  = (float)(tt * g);
  }

  // grid: 48 x-tiles * 55 y-tiles (55*56=3080 >= 3072, masked) * {GNN, LR}
  hess_kernel<<<dim3(GX, GY, GZ), 256, 0, stream>>>(gnn, lr, tg, xraw, st, mp,
                                                    acc, slotmask, tp);

  finalize_kernel<<<1, 1, 0, stream>>>(acc, slotmask, out);
}

// Round 6
// 273.945 us; speedup vs baseline: 3.4614x; 1.0431x over previous
//
#include <hip/hip_runtime.h>
#include <math.h>

#define W    3072
#define HH   3072
#define HOUT 3060       // HH - 12 (valid conv output for 13x13 kernel)
#define TW   64         // output cols per block
#define TH   44         // output rows per block (4 waves x 11 rows)
#define RW   11         // rows per wave
#define XR   56         // xt rows = TH + 12
#define XTS  76         // xt col stride
#define VTS  77         // vt col stride (odd -> scalar reads/writes conflict-free)
#define VTW  (RW*VTS)   // per-wave vt words = 847
#define GX   48
#define GY   70         // 70*44 = 3080 >= 3072 (masked)
#define GZ   2
#define NTHR (GX*GY*GZ*256)
#define NSLOT 64        // accumulator slots, each (slot,acc) on its own 64B line
#define NSTG ((XR*19+255)/256)   // staging iterations per thread = 5

struct HessTaps { float a[13]; float bb[13]; float m[13]; float n[13]; };

// ---- per-block reduction -> one f64 atomic per block ------------------------
// ATOMIC CONTENTION WAS THE SESSION'S HIDDEN SERIALIZER (rounds 0-4): each f64
// atomic is a 32B memory-side RMW; same-line atomics serialize at ~13ns, and
// kernel_dur ~= hot-line atomics * 13ns fit rounds 0-4 within noise. Fix
// (round 5, verified: 798 -> 123us): block-level reduction + slot-spreading
// across 64 lines.
__device__ __forceinline__ void reduce_add(float v, double* a) {
  __shared__ float red[8];
  #pragma unroll
  for (int o = 32; o > 0; o >>= 1) v += __shfl_down(v, o, 64);
  int lane = threadIdx.x & 63, wid = threadIdx.x >> 6;
  if (lane == 0) red[wid] = v;
  __syncthreads();
  if (threadIdx.x == 0) {
    float s = red[0] + red[1] + red[2] + red[3];
    unsafeAtomicAdd(a, (double)s);
  }
  __syncthreads();   // protect red[] for a subsequent call
}

// ---- Hessian + TV + folded gf/mse, both images via gridDim.z ---------------
// 64x44 output tile, 4 waves x 11 rows, wave-local V->H (vt wave-private),
// scalar f32 FMAs (v_pk_fma_f32 is half-rate on gfx950: fp32 peak == scalar
// FMA rate, verified rounds 1-2). Round-6 changes:
//  * TH 56->44: LDS 30608 -> 5 blocks/CU (occupancy ceiling 50% -> 62.5%);
//    we measured 41% against the old 50% ceiling -> latency-bound.
//  * T window preloaded into 5 static float4 regs BEFORE barrier 1: the
//    d-update phase between barriers 2-3 is pure LDS/VALU (was a ~900-cycle
//    global-load bubble convoying all resident waves).
//  * gf/mse global loads also issued before barrier 1 (scalars/float4s only,
//    static indexing -- no dynamic arrays, no spill).
// LDS: xt 56*76*4=17024 + vt 4*847*4=13552 + red 32 = 30608 -> 5 blocks/CU.
__global__ __launch_bounds__(256, 5) void hess_kernel(const float* __restrict__ Gnn,
                                                      const float* __restrict__ Lr,
                                                      const float* __restrict__ T,
                                                      const float* __restrict__ Xr,
                                                      const float* __restrict__ St,
                                                      const float* __restrict__ Mp,
                                                      double* acc, int slotmask,
                                                      HessTaps tp) {
  __shared__ float xt[XR * XTS];
  __shared__ float vt[4 * VTW];
  const float* img = (blockIdx.z == 0) ? Gnn : Lr;
  int oy = blockIdx.y * TH, ox = blockIdx.x * TW;
  int t = threadIdx.x;
  int wv = t >> 6, ln = t & 63;    // wave id 0..3, lane 0..63
  int r0 = wv * RW;

  // load xt (56 rows x 76 cols) as aligned float4 with edge masking
  for (int idx = t; idx < XR * 19; idx += 256) {
    int r = idx / 19, g = idx - r * 19;
    int gr = oy + r, gc = ox + 4 * g;
    float4 v = {0.f, 0.f, 0.f, 0.f};
    if (gr < HH) {
      const float* p = &img[(size_t)gr * W + gc];
      if (gc + 3 < W) v = *(const float4*)p;
      else {
        if (gc < W)     v.x = p[0];
        if (gc + 1 < W) v.y = p[1];
        if (gc + 2 < W) v.z = p[2];
      }
    }
    *(float4*)&xt[r * XTS + 4 * g] = v;
  }

  // ---- preload the T window for the d-update (static 5x float4, masked);
  // latency hides under term-1 compute instead of stalling at barrier 2.
  float4 tr4[NSTG];
  #pragma unroll
  for (int k = 0; k < NSTG; ++k) {
    int idx = t + 256 * k;
    float4 v = {0.f, 0.f, 0.f, 0.f};
    if (idx < XR * 19) {
      int r = idx / 19, g = idx - r * 19;
      int gr = oy + r, gc = ox + 4 * g;
      if (gr < HH) {
        const float* p = &T[(size_t)gr * W + gc];
        if (gc + 3 < W) v = *(const float4*)p;
        else {
          if (gc < W)     v.x = p[0];
          if (gc + 1 < W) v.y = p[1];
          if (gc + 2 < W) v.z = p[2];
        }
      }
    }
    tr4[k] = v;
  }

  // ---- issue gf/mse global loads now; latency hides under the whole conv
  int bid = (blockIdx.z * GY + blockIdx.y) * GX + blockIdx.x;
  int i0 = bid * 256 + t;
  int i1 = i0 + NTHR;
  const int n4 = (W * HH) / 4;
  float4 ga0 = ((const float4*)Xr)[i0];    // i0 < NTHR <= n4 always
  float4 gb0 = ((const float4*)St)[i0];
  float4 ga1 = {0.f, 0.f, 0.f, 0.f}, gb1 = ga1;
  bool has1 = (i1 < n4);
  if (has1) { ga1 = ((const float4*)Xr)[i1]; gb1 = ((const float4*)St)[i1]; }
  float mT = 0.f, mG = 0.f, mM = 0.f;
  bool hasm = (i0 < 384 * 384);
  if (hasm) {
    int si = i0 / 384, sj = i0 - si * 384;
    int id = si * 8 * W + sj * 8;
    mT = T[id]; mG = Gnn[id]; mM = Mp[id];
  }
  __builtin_amdgcn_sched_barrier(0);

  __syncthreads();     // barrier 1: xt staged

  float tvl = 0.f;   // TV accumulator
  float hl  = 0.f;   // Hessian accumulator

  // TV Dx term on x: |x(r,c) - x(r,c+1)|  (lanes contiguous -> free)
  {
    int gc = ox + ln;
    if (gc < W - 1) {
      #pragma unroll
      for (int i = 0; i < RW; ++i) {
        int r = r0 + i;
        if (oy + r < HH)
          tvl += fabsf(xt[r * XTS + ln] - xt[r * XTS + ln + 1]);
      }
    }
  }

  // ---- V pass: main 64 cols (all lanes) + dense halo (12x11=132 outputs,
  // <=3 per lane). Per-output tap order u-ascending -> bitwise identical.
  #define VPASS(TAP)                                                        \
    {                                                                       \
      /* main: lane = col ln; 11 sliding accumulators over 23-row window */ \
      float oA[RW];                                                         \
      _Pragma("unroll")                                                     \
      for (int i = 0; i < RW; ++i) oA[i] = 0.f;                             \
      _Pragma("unroll")                                                     \
      for (int u = 0; u < RW + 12; ++u) {                                   \
        float xA = xt[(r0 + u) * XTS + ln];                                 \
        _Pragma("unroll")                                                   \
        for (int i = 0; i < RW; ++i) {                                      \
          int kk = u - i;                                                   \
          if (kk >= 0 && kk <= 12) oA[i] = fmaf((TAP)[kk], xA, oA[i]);      \
        }                                                                   \
      }                                                                     \
      float* vw = &vt[wv * VTW + ln];                                       \
      _Pragma("unroll")                                                     \
      for (int i = 0; i < RW; ++i) vw[i * VTS] = oA[i];                     \
      /* halo: 12 cols x 11 rows = 132 outputs, <=3 per lane */             \
      _Pragma("unroll")                                                     \
      for (int k = 0; k < 3; ++k) {                                         \
        int o = ln + 64 * k;                                                \
        if (o < 12 * RW) {                                                  \
          int row = o / 12, hc = o - row * 12;                              \
          const float* xp = &xt[(r0 + row) * XTS + 64 + hc];                \
          float s = 0.f;                                                    \
          _Pragma("unroll")                                                 \
          for (int u = 0; u < 13; ++u) s = fmaf((TAP)[u], xp[u * XTS], s);  \
          vt[wv * VTW + row * VTS + 64 + hc] = s;                           \
        }                                                                   \
      }                                                                     \
    }

  // ---- H pass: scalar sliding reads of the SAME wave's vt rows (stride 77
  // -> <=2 lanes/bank); 16 register accumulators, tap order j-ascending.
  #define HSECOND(TAP, WGT)                                                 \
    {                                                                       \
      int r14 = ln & 15, cg = ln >> 4;                                      \
      if (r14 < RW) {                                                       \
        const float* vrow = &vt[wv * VTW + r14 * VTS + cg * 16];            \
        float o_[16];                                                       \
        _Pragma("unroll")                                                   \
        for (int jj = 0; jj < 16; ++jj) o_[jj] = 0.f;                       \
        _Pragma("unroll")                                                   \
        for (int j = 0; j < 28; ++j) {                                      \
          float v = vrow[j];                                                \
          _Pragma("unroll")                                                 \
          for (int jj = 0; jj < 16; ++jj) {                                 \
            int kk = j - jj;                                                \
            if (kk >= 0 && kk <= 12) o_[jj] = fmaf((TAP)[kk], v, o_[jj]);   \
          }                                                                 \
        }                                                                   \
        int gr = oy + r0 + r14;                                             \
        int gc0 = ox + cg * 16;                                             \
        float wr = (gr < HOUT) ? (WGT) : 0.f;                               \
        _Pragma("unroll")                                                   \
        for (int jj = 0; jj < 16; ++jj) {                                   \
          float m_ = (gc0 + jj < HOUT) ? wr : 0.f;                          \
          hl = fmaf(m_, fabsf(o_[jj]), hl);                                 \
        }                                                                   \
      }                                                                     \
    }

  // term 1: conv(x, Gxx) = vert bb, horiz a   (vt is wave-private: no barrier)
  VPASS(tp.bb);
  HSECOND(tp.a, 1.0f);

  // d = x - target (in place), using the preloaded T registers: pure
  // LDS/VALU between the barriers -- no global-load bubble.
  __syncthreads();     // barrier 2
  #pragma unroll
  for (int k = 0; k < NSTG; ++k) {
    int idx = t + 256 * k;
    if (idx < XR * 19) {
      int r = idx / 19, g = idx - r * 19;
      float4 cur = *(float4*)&xt[r * XTS + 4 * g];
      cur.x -= tr4[k].x; cur.y -= tr4[k].y;
      cur.z -= tr4[k].z; cur.w -= tr4[k].w;
      *(float4*)&xt[r * XTS + 4 * g] = cur;
    }
  }
  __syncthreads();     // barrier 3

  // TV Dy term on d: |d(r,c) - d(r+1,c)|, r < HH-1
  {
    int gc = ox + ln;
    if (gc < W) {
      #pragma unroll
      for (int i = 0; i < RW; ++i) {
        int r = r0 + i;
        if (oy + r < HH - 1)
          tvl += fabsf(xt[r * XTS + ln] - xt[(r + 1) * XTS + ln]);
      }
    }
  }

  // term 2: conv(d, Gyy) = vert a, horiz bb
  VPASS(tp.a);
  HSECOND(tp.bb, 1.0f);

  // term 3: conv(d, Gxy) = vert m, horiz n, weight 2 (isotropic)
  VPASS(tp.m);
  HSECOND(tp.n, 2.0f);

  // folded gf term (gf(x,x)==x exactly -> sum|st-x|) + sampled L1*map;
  // operands loaded before barrier 1, latency hidden under the conv.
  float gm = fabsf(gb0.x - ga0.x) + fabsf(gb0.y - ga0.y)
           + fabsf(gb0.z - ga0.z) + fabsf(gb0.w - ga0.w);
  if (has1)
    gm += fabsf(gb1.x - ga1.x) + fabsf(gb1.y - ga1.y)
        + fabsf(gb1.z - ga1.z) + fabsf(gb1.w - ga1.w);
  if (hasm) gm += fabsf(mT - mG) * mM;

  // slot-spread accumulators: (slot, j) at byte offset slot*256 + j*64
  // -> every target address on its own 64B line; ~315 atomics/line total.
  int slot = bid & slotmask;
  double* base = acc + (size_t)slot * 32;
  reduce_add(gm,  base);        // j=0
  reduce_add(tvl, base + 8);    // j=1
  reduce_add(hl,  base + 16);   // j=2
}

// ---- combine ---------------------------------------------------------------
__global__ void finalize_kernel(const double* acc, int slotmask, float* out) {
  double s0 = 0.0, s1 = 0.0, s3 = 0.0;
  for (int s = 0; s <= slotmask; ++s) {
    s0 += acc[s * 32];
    s1 += acc[s * 32 + 8];
    s3 += acc[s * 32 + 16];
  }
  out[0] = (float)(s0 + 0.1 * s1 + 0.5 * s3);
}

extern "C" void kernel_launch(void* const* d_in, const int* in_sizes, int n_in,
                              void* d_out, int out_size, void* d_ws, size_t ws_size,
                              hipStream_t stream) {
  const float* xraw = (const float*)d_in[0];   // outputGNNraw
  const float* gnn  = (const float*)d_in[1];   // outputGNN
  const float* lr   = (const float*)d_in[2];   // outputLR
  const float* st   = (const float*)d_in[3];   // smoothedTarget
  const float* tg   = (const float*)d_in[4];   // targets
  const float* mp   = (const float*)d_in[5];   // map
  float* out = (float*)d_out;

  // slot count: NSLOT if the workspace allows (needs NSLOT*256 B), else the
  // largest power of two that fits.
  int nslot = NSLOT;
  while (nslot > 1 && (size_t)nslot * 256 > ws_size) nslot >>= 1;
  int slotmask = nslot - 1;

  double* acc = (double*)d_ws;
  hipMemsetAsync(d_ws, 0, (size_t)nslot * 256, stream);

  // separable Hessian-of-Gaussian taps (sigma=1, t = -6..6):
  //   Gxx[i,j] = bb(i)*a(j); Gyy[i,j] = a(i)*bb(j); Gxy[i,j] = m(i)*n(j)
  HessTaps tp;
  const double PI2 = 6.283185307179586476925287;
  for (int k = 0; k < 13; ++k) {
    double tt = (double)(k - 6);
    double g = exp(-0.5 * tt * tt);
    tp.a[k]  = (float)((tt * tt - 1.0) * g / PI2);
    tp.bb[k] = (float)g;
    tp.m[k]  = (float)(tt * g / PI2);
    tp.n[k]  = (float)(tt * g);
  }

  // grid: 48 x-tiles * 70 y-tiles (70*44=3080 >= 3072, masked) * {GNN, LR}
  hess_kernel<<<dim3(GX, GY, GZ), 256, 0, stream>>>(gnn, lr, tg, xraw, st, mp,
                                                    acc, slotmask, tp);

  finalize_kernel<<<1, 1, 0, stream>>>(acc, slotmask, out);
}